// Round 3
// baseline (46202.579 us; speedup 1.0000x reference)
//
#include <hip/hip_runtime.h>

#define NB 256      // batch
#define NT 512      // time steps
#define NH 1024     // hidden
#define BH (NB * NH)
#define GRID_WGS 256
#define BLOCK_THREADS 512
#define GSTRIDE (GRID_WGS * BLOCK_THREADS)

typedef __attribute__((ext_vector_type(8))) __bf16 bfrag;
typedef __attribute__((ext_vector_type(4))) float f32x4;
typedef __attribute__((ext_vector_type(8))) unsigned short u16x8;

// h-state double buffers: h(t) lives in buf[t&1]
__device__ unsigned short g_h1[2 * BH];
__device__ unsigned short g_h2[2 * BH];

// custom grid barrier state (monotonic; never reset -> graph-replay safe)
__device__ unsigned g_arrive = 0;
__device__ unsigned g_epoch  = 0;

__device__ __forceinline__ unsigned short f2bf(float f) {
  union { float f; unsigned u; } v; v.f = f;
  unsigned r = v.u + 0x7FFFu + ((v.u >> 16) & 1u);  // RTE
  return (unsigned short)(r >> 16);
}
__device__ __forceinline__ float bf2f(unsigned short u) {
  union { unsigned u; float f; } v; v.u = ((unsigned)u) << 16;
  return v.f;
}

// convert 8 consecutive fp32 -> bf16 fragment
__device__ __forceinline__ bfrag cvt8(const float* __restrict__ p) {
  f32x4 a = *reinterpret_cast<const f32x4*>(p);
  f32x4 b = *reinterpret_cast<const f32x4*>(p + 4);
  u16x8 u;
#pragma unroll
  for (int i = 0; i < 4; ++i) { u[i] = f2bf(a[i]); u[i + 4] = f2bf(b[i]); }
  union { u16x8 u; bfrag b; } c; c.u = u; return c.b;
}

// custom grid barrier; k = 0-based barrier index within this launch,
// e_base = g_epoch sampled at kernel start (thread 0 only holds it).
__device__ __forceinline__ void grid_bar(int k, unsigned e_base) {
  __threadfence();        // release: drain my global writes to coherence point
  __syncthreads();        // whole WG done + fenced
  if (threadIdx.x == 0) {
    const unsigned target_epoch = e_base + (unsigned)k + 1u;
    unsigned old = __hip_atomic_fetch_add(&g_arrive, 1u, __ATOMIC_RELAXED,
                                          __HIP_MEMORY_SCOPE_AGENT);
    if (old == e_base * GRID_WGS + (unsigned)(k + 1) * GRID_WGS - 1u) {
      __hip_atomic_store(&g_epoch, target_epoch, __ATOMIC_RELEASE,
                         __HIP_MEMORY_SCOPE_AGENT);
    } else {
      while (__hip_atomic_load(&g_epoch, __ATOMIC_RELAXED,
                               __HIP_MEMORY_SCOPE_AGENT) < target_epoch)
        __builtin_amdgcn_s_sleep(1);
    }
  }
  __syncthreads();
  // acquire: every thread invalidates stale cached state
  (void)__hip_atomic_load(&g_epoch, __ATOMIC_ACQUIRE, __HIP_MEMORY_SCOPE_AGENT);
}

// out(t)[r,c] = dot(h2(t)[r,:], Wlin[c,:]) + blin[c]; bid<64, waves 0..3, 1 row/wave
__device__ __forceinline__ void out_dot(const unsigned short* __restrict__ h2,
                                        const float* __restrict__ Wlin,
                                        const float* __restrict__ blin,
                                        float* __restrict__ out,
                                        int bid, int wid, int lane, int t) {
  const int r_g = (bid >> 3) * 32 + (bid & 7) * 4 + wid;  // 0..255
  const int c = lane >> 5;
  const int l32 = lane & 31;
  const unsigned short* hp = h2 + r_g * NH + l32 * 32;
  const float* wl = Wlin + c * NH + l32 * 32;
  float s = 0.f;
#pragma unroll
  for (int j = 0; j < 32; j += 8) {
    u16x8 hv = *reinterpret_cast<const u16x8*>(hp + j);
#pragma unroll
    for (int e = 0; e < 8; ++e) s = fmaf(bf2f(hv[e]), wl[j + e], s);
  }
#pragma unroll
  for (int m = 1; m < 32; m <<= 1) s += __shfl_xor(s, m);
  if (l32 == 0) out[r_g * (2 * NT) + c * NT + t] = s + blin[c];
}

__global__ void __launch_bounds__(BLOCK_THREADS, 2) rnn_kernel(
    const float* __restrict__ x,     // [B][2][T]
    const float* __restrict__ Wi1,   // [H][2]
    const float* __restrict__ Whh1,  // [H][H]
    const float* __restrict__ Wih2,  // [H][H]
    const float* __restrict__ Whh2,  // [H][H]
    const float* __restrict__ bih1,
    const float* __restrict__ bhh1,
    const float* __restrict__ bih2,
    const float* __restrict__ bhh2,
    const float* __restrict__ Wlin,  // [2][H]
    const float* __restrict__ blin,  // [2]
    float* __restrict__ out)         // [B][2][T]
{
  const int bid = blockIdx.x;
  const int tid = threadIdx.x;
  const int w = tid >> 6, lane = tid & 63;
  const int mb = bid >> 6, nb = bid & 63;   // 4 row-tiles x 64 col-tiles

  // sample barrier epoch base BEFORE any barrier use (stable: epoch cannot
  // advance past e_base until this WG arrives at barrier 0)
  unsigned e_base = 0;
  if (tid == 0)
    e_base = __hip_atomic_load(&g_epoch, __ATOMIC_RELAXED, __HIP_MEMORY_SCOPE_AGENT);

  // zero the parity-1 buffers (the t = -1 state)
  {
    const int gtid = bid * BLOCK_THREADS + tid;
    for (int i = gtid; i < BH; i += GSTRIDE) {
      g_h1[BH + i] = 0;
      g_h2[BH + i] = 0;
    }
  }

  // ---- persistent weight fragments: this wave's K-slice [w*128, w*128+128)
  // B-frag mapping: col = lane&15, k = (lane>>4)*8 + j
  const int fr = lane & 15;
  const int ko = (lane >> 4) << 3;        // 0,8,16,24
  const int kbase = w * 128;
  const int colW = nb * 16 + fr;
  bfrag w1[4], w2i[4], w2h[4];
#pragma unroll
  for (int st = 0; st < 4; ++st) {
    const int off = colW * NH + kbase + st * 32 + ko;
    w1[st]  = cvt8(Whh1 + off);
    w2i[st] = cvt8(Wih2 + off);
    w2h[st] = cvt8(Whh2 + off);
  }

  // ---- per-thread epilogue constants (2 adjacent cols of one row)
  const int idx = tid * 2;
  const int rl = idx >> 4, cl = idx & 15;          // local row 0..63, col (even)
  const int grow = mb * 64 + rl, gcol = nb * 16 + cl;
  const float b1s0 = bih1[gcol] + bhh1[gcol];
  const float b1s1 = bih1[gcol + 1] + bhh1[gcol + 1];
  const float b2s0 = bih2[gcol] + bhh2[gcol];
  const float b2s1 = bih2[gcol + 1] + bhh2[gcol + 1];
  const float wi00 = Wi1[gcol * 2],       wi01 = Wi1[gcol * 2 + 1];
  const float wi10 = Wi1[(gcol + 1) * 2], wi11 = Wi1[(gcol + 1) * 2 + 1];
  const float* xrow = x + grow * (2 * NT);

  __shared__ float redA[8][64][18];
  __shared__ float redB[8][64][18];

  const int arow0 = mb * 64 + fr;     // A-frag row base (+ mf*16)
  const int prow = (lane >> 4) << 2;  // C/D row base within 16x16 frag

  grid_bar(0, e_base);

  // phase p: A(p)=h1(p) [p<NT] || B(p-1)=h2(p-1) [p>=1] || out(p-2) [p>=2]
  for (int p = 0; p <= NT; ++p) {
    const unsigned short* h1_prev = g_h1 + ((p + 1) & 1) * BH; // h1(p-1)
    const unsigned short* h2_pp   = g_h2 + (p & 1) * BH;       // h2(p-2)
    unsigned short* h1_cur = g_h1 + (p & 1) * BH;              // h1(p)
    unsigned short* h2_cur = g_h2 + ((p + 1) & 1) * BH;        // h2(p-1)

    f32x4 accA[4] = {}; f32x4 accB[4] = {};

#pragma unroll
    for (int mf = 0; mf < 4; ++mf) {
      const unsigned short* pa1 = h1_prev + (arow0 + mf * 16) * NH + kbase + ko;
      const unsigned short* pa2 = h2_pp   + (arow0 + mf * 16) * NH + kbase + ko;
#pragma unroll
      for (int st = 0; st < 4; ++st) {
        bfrag a1 = *reinterpret_cast<const bfrag*>(pa1 + st * 32);
        if (p < NT)
          accA[mf] = __builtin_amdgcn_mfma_f32_16x16x32_bf16(a1, w1[st], accA[mf], 0, 0, 0);
        if (p >= 1) {
          accB[mf] = __builtin_amdgcn_mfma_f32_16x16x32_bf16(a1, w2i[st], accB[mf], 0, 0, 0);
          bfrag a2 = *reinterpret_cast<const bfrag*>(pa2 + st * 32);
          accB[mf] = __builtin_amdgcn_mfma_f32_16x16x32_bf16(a2, w2h[st], accB[mf], 0, 0, 0);
        }
      }
    }

    // write k-partials to LDS  (C/D: col = lane&15, row = (lane>>4)*4 + r)
#pragma unroll
    for (int mf = 0; mf < 4; ++mf) {
#pragma unroll
      for (int r = 0; r < 4; ++r) {
        redA[w][mf * 16 + prow + r][fr] = accA[mf][r];
        redB[w][mf * 16 + prow + r][fr] = accB[mf][r];
      }
    }
    __syncthreads();

    // 8-way k-reduction + fused epilogue (2 adjacent cols per thread)
    float sA0 = 0.f, sA1 = 0.f, sB0 = 0.f, sB1 = 0.f;
#pragma unroll
    for (int u = 0; u < 8; ++u) {
      sA0 += redA[u][rl][cl];  sA1 += redA[u][rl][cl + 1];
      sB0 += redB[u][rl][cl];  sB1 += redB[u][rl][cl + 1];
    }
    if (p < NT) {
      const float x0 = xrow[p], x1 = xrow[NT + p];
      const float v0 = sA0 + b1s0 + x0 * wi00 + x1 * wi01;
      const float v1 = sA1 + b1s1 + x0 * wi10 + x1 * wi11;
      const unsigned pack = (unsigned)f2bf(tanhf(v0)) | ((unsigned)f2bf(tanhf(v1)) << 16);
      *reinterpret_cast<unsigned*>(h1_cur + grow * NH + gcol) = pack;
    }
    if (p >= 1) {
      const float v0 = sB0 + b2s0;
      const float v1 = sB1 + b2s1;
      const unsigned pack = (unsigned)f2bf(tanhf(v0)) | ((unsigned)f2bf(tanhf(v1)) << 16);
      *reinterpret_cast<unsigned*>(h2_cur + grow * NH + gcol) = pack;
    }
    if (p >= 2 && bid < 64 && w < 4)
      out_dot(h2_pp, Wlin, blin, out, bid, w, lane, p - 2);

    grid_bar(p + 1, e_base);
  }

  // final output t = NT-1: h2(NT-1) lives in buf[1]
  if (bid < 64 && w < 4)
    out_dot(g_h2 + BH, Wlin, blin, out, bid, w, lane, NT - 1);
}

extern "C" void kernel_launch(void* const* d_in, const int* in_sizes, int n_in,
                              void* d_out, int out_size, void* d_ws, size_t ws_size,
                              hipStream_t stream) {
  (void)in_sizes; (void)n_in; (void)d_ws; (void)ws_size; (void)out_size;
  const float* x    = (const float*)d_in[0];
  const float* Wi1  = (const float*)d_in[1];
  const float* Whh1 = (const float*)d_in[2];
  const float* bih1 = (const float*)d_in[3];
  const float* bhh1 = (const float*)d_in[4];
  const float* Wih2 = (const float*)d_in[5];
  const float* Whh2 = (const float*)d_in[6];
  const float* bih2 = (const float*)d_in[7];
  const float* bhh2 = (const float*)d_in[8];
  const float* Wlin = (const float*)d_in[9];
  const float* blin = (const float*)d_in[10];
  float* out = (float*)d_out;

  void* args[] = { (void*)&x, (void*)&Wi1, (void*)&Whh1, (void*)&Wih2, (void*)&Whh2,
                   (void*)&bih1, (void*)&bhh1, (void*)&bih2, (void*)&bhh2,
                   (void*)&Wlin, (void*)&blin, (void*)&out };
  hipLaunchCooperativeKernel((void*)rnn_kernel, dim3(GRID_WGS), dim3(BLOCK_THREADS),
                             args, 0, stream);
}

// Round 4
// 8679.828 us; speedup vs baseline: 5.3230x; 5.3230x over previous
//
#include <hip/hip_runtime.h>

#define NB 256      // batch
#define NT 512      // time steps
#define NH 1024     // hidden
#define BH (NB * NH)
#define GRID_WGS 256
#define BLOCK 512

typedef __attribute__((ext_vector_type(8))) __bf16 bfrag;
typedef __attribute__((ext_vector_type(4))) float f32x4;
typedef __attribute__((ext_vector_type(8))) unsigned short u16x8;

// h-state double buffers: h(t) lives in buf[t&1]
__device__ unsigned short g_h1[2 * BH];
__device__ unsigned short g_h2[2 * BH];
// per-WG monotonic phase flags (never reset -> graph-replay safe), grouped by 32
__device__ __attribute__((aligned(128))) unsigned g_flag[GRID_WGS];

__device__ __forceinline__ unsigned short f2bf(float f) {
  union { float f; unsigned u; } v; v.f = f;
  unsigned r = v.u + 0x7FFFu + ((v.u >> 16) & 1u);  // RTE
  return (unsigned short)(r >> 16);
}
__device__ __forceinline__ float bf2f(unsigned short u) {
  union { unsigned u; float f; } v; v.u = ((unsigned)u) << 16;
  return v.f;
}

// convert 8 consecutive fp32 -> bf16 fragment (weights; plain cached loads)
__device__ __forceinline__ bfrag cvt8(const float* __restrict__ p) {
  f32x4 a = *reinterpret_cast<const f32x4*>(p);
  f32x4 b = *reinterpret_cast<const f32x4*>(p + 4);
  u16x8 u;
#pragma unroll
  for (int i = 0; i < 4; ++i) { u[i] = f2bf(a[i]); u[i + 4] = f2bf(b[i]); }
  union { u16x8 u; bfrag b; } c; c.u = u; return c.b;
}

// coherent (sc0 sc1) 16B fragment load as 2x 8B relaxed agent atomics
union frag_u { unsigned long long q[2]; bfrag b; u16x8 s; };
__device__ __forceinline__ frag_u ld_frag(const unsigned short* p) {
  frag_u u;
  u.q[0] = __hip_atomic_load((unsigned long long*)p,       __ATOMIC_RELAXED, __HIP_MEMORY_SCOPE_AGENT);
  u.q[1] = __hip_atomic_load((unsigned long long*)(p + 4), __ATOMIC_RELAXED, __HIP_MEMORY_SCOPE_AGENT);
  return u;
}
__device__ __forceinline__ void st4(unsigned short* p, unsigned v) {
  __hip_atomic_store((unsigned*)p, v, __ATOMIC_RELAXED, __HIP_MEMORY_SCOPE_AGENT);
}

// wait until all 32 group flags >= tgt (all waves poll; lanes 0..31 hold flags)
__device__ __forceinline__ void group_wait(unsigned* flags, int lane, unsigned tgt) {
  unsigned f = tgt;
  if (lane < 32) f = __hip_atomic_load(&flags[lane], __ATOMIC_RELAXED, __HIP_MEMORY_SCOPE_AGENT);
  while (__any((int)(f < tgt))) {
    __builtin_amdgcn_s_sleep(1);
    asm volatile("" ::: "memory");
    if (lane < 32) f = __hip_atomic_load(&flags[lane], __ATOMIC_RELAXED, __HIP_MEMORY_SCOPE_AGENT);
  }
}

// out(t)[r,c]: waves 0,1 of each WG; wave w computes col c=w for row r = mb*32+nb
__device__ __forceinline__ void out_row(const unsigned short* h2, int r_g, int w,
                                        int lane, const float* __restrict__ Wlin,
                                        const float* __restrict__ blin,
                                        float* __restrict__ out, int t) {
  const unsigned short* hp = h2 + r_g * NH + lane * 16;
  const float* wl = Wlin + w * NH + lane * 16;
  float s = 0.f;
#pragma unroll
  for (int j = 0; j < 2; ++j) {
    frag_u hv = ld_frag(hp + j * 8);
#pragma unroll
    for (int e = 0; e < 8; ++e) s = fmaf(bf2f(hv.s[e]), wl[j * 8 + e], s);
  }
#pragma unroll
  for (int m = 1; m < 64; m <<= 1) s += __shfl_xor(s, m);
  if (lane == 0) out[r_g * (2 * NT) + w * NT + t] = s + blin[w];
}

__global__ void __launch_bounds__(BLOCK, 1) rnn_kernel(
    const float* __restrict__ x,     // [B][2][T]
    const float* __restrict__ Wi1,   // [H][2]
    const float* __restrict__ Whh1,  // [H][H]
    const float* __restrict__ Wih2,  // [H][H]
    const float* __restrict__ Whh2,  // [H][H]
    const float* __restrict__ bih1,
    const float* __restrict__ bhh1,
    const float* __restrict__ bih2,
    const float* __restrict__ bhh2,
    const float* __restrict__ Wlin,  // [2][H]
    const float* __restrict__ blin,  // [2]
    float* __restrict__ out)         // [B][2][T]
{
  const int bid = blockIdx.x, tid = threadIdx.x;
  const int w = tid >> 6, lane = tid & 63;
  const int mb = bid >> 5, nb = bid & 31;   // group mb: rows [mb*32,+32); WG cols [nb*32,+32)
  unsigned* flags = g_flag + mb * 32;

  // my own flag only advances when I store it -> stable base sample
  const unsigned base = __hip_atomic_load(&flags[nb], __ATOMIC_RELAXED, __HIP_MEMORY_SCOPE_AGENT);

  // zero my group's rows of the parity-1 buffers (the t = -1 state), coherent stores
  {
    unsigned* z1 = (unsigned*)(g_h1 + BH + mb * 32 * NH);
    unsigned* z2 = (unsigned*)(g_h2 + BH + mb * 32 * NH);
    for (int i = tid; i < 16 * NH; i += BLOCK) {
      __hip_atomic_store(&z1[i], 0u, __ATOMIC_RELAXED, __HIP_MEMORY_SCOPE_AGENT);
      __hip_atomic_store(&z2[i], 0u, __ATOMIC_RELAXED, __HIP_MEMORY_SCOPE_AGENT);
    }
  }

  // ---- persistent weight fragments: wave = (col-half ch, k-quarter kq)
  const int fr = lane & 15;
  const int ko = (lane >> 4) << 3;        // 0,8,16,24
  const int ch = w & 1, kq = w >> 1;
  const int kbase = kq * 256;
  const int colW = nb * 32 + ch * 16 + fr;
  bfrag w1[8], w2i[8], w2h[8];
#pragma unroll
  for (int st = 0; st < 8; ++st) {
    const int off = colW * NH + kbase + st * 32 + ko;
    w1[st]  = cvt8(Whh1 + off);
    w2i[st] = cvt8(Wih2 + off);
    w2h[st] = cvt8(Whh2 + off);
  }

  // ---- per-thread epilogue constants (2 adjacent cols of one row)
  const int rl = tid >> 4, cl = (tid & 15) * 2;    // row 0..31, col even
  const int grow = mb * 32 + rl, gcol = nb * 32 + cl;
  const float b1s0 = bih1[gcol] + bhh1[gcol];
  const float b1s1 = bih1[gcol + 1] + bhh1[gcol + 1];
  const float b2s0 = bih2[gcol] + bhh2[gcol];
  const float b2s1 = bih2[gcol + 1] + bhh2[gcol + 1];
  const float wi00 = Wi1[gcol * 2],       wi01 = Wi1[gcol * 2 + 1];
  const float wi10 = Wi1[(gcol + 1) * 2], wi11 = Wi1[(gcol + 1) * 2 + 1];
  const float* xrow = x + grow * (2 * NT);

  __shared__ float redA[4][32][36];
  __shared__ float redB[4][32][36];

  const int arow0 = mb * 32 + fr;     // A-frag row base (+ mf*16)
  const int prow = (lane >> 4) << 2;  // C/D row base within 16x16 frag
  const int r_g = mb * 32 + nb;       // this WG's out row

  // preamble complete -> flag = base+1
  asm volatile("s_waitcnt vmcnt(0)" ::: "memory");
  __syncthreads();
  if (tid == 0)
    __hip_atomic_store(&flags[nb], base + 1u, __ATOMIC_RELAXED, __HIP_MEMORY_SCOPE_AGENT);

  // phase p: A(p)=h1(p) [p<NT] || B(p-1)=h2(p-1) [p>=1] || out(p-2) [p>=2]
  for (int p = 0; p <= NT; ++p) {
    const unsigned short* h1_prev = g_h1 + ((p + 1) & 1) * BH; // h1(p-1)
    const unsigned short* h2_pp   = g_h2 + (p & 1) * BH;       // h2(p-2)
    unsigned short* h1_cur = g_h1 + (p & 1) * BH;              // h1(p)
    unsigned short* h2_cur = g_h2 + ((p + 1) & 1) * BH;        // h2(p-1)

    group_wait(flags, lane, base + 1u + (unsigned)p);
    __builtin_amdgcn_sched_barrier(0);   // keep loads below the wait

    // out projection for t=p-2 (data ready since phase p-1), waves 0,1
    if (p >= 2 && w < 2)
      out_row(h2_pp, r_g, w, lane, Wlin, blin, out, p - 2);

    f32x4 accA[2] = {}; f32x4 accB[2] = {};
#pragma unroll
    for (int mf = 0; mf < 2; ++mf) {
      const unsigned short* pa1 = h1_prev + (arow0 + mf * 16) * NH + kbase + ko;
      const unsigned short* pa2 = h2_pp   + (arow0 + mf * 16) * NH + kbase + ko;
#pragma unroll
      for (int st = 0; st < 8; ++st) {
        frag_u a1 = ld_frag(pa1 + st * 32);
        if (p < NT)
          accA[mf] = __builtin_amdgcn_mfma_f32_16x16x32_bf16(a1.b, w1[st], accA[mf], 0, 0, 0);
        if (p >= 1) {
          accB[mf] = __builtin_amdgcn_mfma_f32_16x16x32_bf16(a1.b, w2i[st], accB[mf], 0, 0, 0);
          frag_u a2 = ld_frag(pa2 + st * 32);
          accB[mf] = __builtin_amdgcn_mfma_f32_16x16x32_bf16(a2.b, w2h[st], accB[mf], 0, 0, 0);
        }
      }
    }

    // k-partials to LDS  (C/D: col = lane&15, row = (lane>>4)*4 + r)
#pragma unroll
    for (int mf = 0; mf < 2; ++mf) {
#pragma unroll
      for (int r = 0; r < 4; ++r) {
        redA[kq][mf * 16 + prow + r][ch * 16 + fr] = accA[mf][r];
        redB[kq][mf * 16 + prow + r][ch * 16 + fr] = accB[mf][r];
      }
    }
    __syncthreads();

    // 4-way k-reduction + fused epilogue (2 adjacent cols per thread)
    float sA0 = 0.f, sA1 = 0.f, sB0 = 0.f, sB1 = 0.f;
#pragma unroll
    for (int u = 0; u < 4; ++u) {
      const float2 a = *reinterpret_cast<const float2*>(&redA[u][rl][cl]);
      const float2 b = *reinterpret_cast<const float2*>(&redB[u][rl][cl]);
      sA0 += a.x; sA1 += a.y; sB0 += b.x; sB1 += b.y;
    }
    if (p < NT) {
      const float x0 = xrow[p], x1 = xrow[NT + p];
      const float v0 = sA0 + b1s0 + x0 * wi00 + x1 * wi01;
      const float v1 = sA1 + b1s1 + x0 * wi10 + x1 * wi11;
      st4(h1_cur + grow * NH + gcol,
          (unsigned)f2bf(tanhf(v0)) | ((unsigned)f2bf(tanhf(v1)) << 16));
    }
    if (p >= 1) {
      const float v0 = sB0 + b2s0;
      const float v1 = sB1 + b2s1;
      st4(h2_cur + grow * NH + gcol,
          (unsigned)f2bf(tanhf(v0)) | ((unsigned)f2bf(tanhf(v1)) << 16));
    }

    // release: all my coherent writes acked, then publish phase completion
    asm volatile("s_waitcnt vmcnt(0)" ::: "memory");
    __syncthreads();
    if (tid == 0)
      __hip_atomic_store(&flags[nb], base + 2u + (unsigned)p, __ATOMIC_RELAXED, __HIP_MEMORY_SCOPE_AGENT);
  }

  // final output t = NT-1: needs h2(NT-1) (written at phase NT by my group)
  group_wait(flags, lane, base + 2u + (unsigned)NT);
  if (w < 2)
    out_row(g_h2 + BH, r_g, w, lane, Wlin, blin, out, NT - 1);
}

extern "C" void kernel_launch(void* const* d_in, const int* in_sizes, int n_in,
                              void* d_out, int out_size, void* d_ws, size_t ws_size,
                              hipStream_t stream) {
  (void)in_sizes; (void)n_in; (void)d_ws; (void)ws_size; (void)out_size;
  const float* x    = (const float*)d_in[0];
  const float* Wi1  = (const float*)d_in[1];
  const float* Whh1 = (const float*)d_in[2];
  const float* bih1 = (const float*)d_in[3];
  const float* bhh1 = (const float*)d_in[4];
  const float* Wih2 = (const float*)d_in[5];
  const float* Whh2 = (const float*)d_in[6];
  const float* bih2 = (const float*)d_in[7];
  const float* bhh2 = (const float*)d_in[8];
  const float* Wlin = (const float*)d_in[9];
  const float* blin = (const float*)d_in[10];
  float* out = (float*)d_out;

  void* args[] = { (void*)&x, (void*)&Wi1, (void*)&Whh1, (void*)&Wih2, (void*)&Whh2,
                   (void*)&bih1, (void*)&bhh1, (void*)&bih2, (void*)&bhh2,
                   (void*)&Wlin, (void*)&blin, (void*)&out };
  hipLaunchCooperativeKernel((void*)rnn_kernel, dim3(GRID_WGS), dim3(BLOCK),
                             args, 0, stream);
}

// Round 5
// 5229.435 us; speedup vs baseline: 8.8351x; 1.6598x over previous
//
#include <hip/hip_runtime.h>

#define NB 256      // batch
#define NT 512      // time steps
#define NH 1024     // hidden
#define BH (NB * NH)
#define GRID_WGS 256
#define BLOCK 512

typedef __attribute__((ext_vector_type(8))) __bf16 bfrag;
typedef __attribute__((ext_vector_type(4))) float f32x4;
typedef __attribute__((ext_vector_type(8))) unsigned short u16x8;

// h-state double buffers: h(t) lives in buf[t&1]
__device__ unsigned short g_h1[2 * BH];
__device__ unsigned short g_h2[2 * BH];
// per-WG monotonic phase flags (never reset -> graph-replay safe), grouped by 32
__device__ __attribute__((aligned(128))) unsigned g_flag[GRID_WGS];

__device__ __forceinline__ unsigned short f2bf(float f) {
  union { float f; unsigned u; } v; v.f = f;
  unsigned r = v.u + 0x7FFFu + ((v.u >> 16) & 1u);  // RTE
  return (unsigned short)(r >> 16);
}
__device__ __forceinline__ float bf2f(unsigned short u) {
  union { unsigned u; float f; } v; v.u = ((unsigned)u) << 16;
  return v.f;
}

// convert 8 consecutive fp32 -> bf16 fragment (weights; plain cached loads)
__device__ __forceinline__ bfrag cvt8(const float* __restrict__ p) {
  f32x4 a = *reinterpret_cast<const f32x4*>(p);
  f32x4 b = *reinterpret_cast<const f32x4*>(p + 4);
  u16x8 u;
#pragma unroll
  for (int i = 0; i < 4; ++i) { u[i] = f2bf(a[i]); u[i + 4] = f2bf(b[i]); }
  union { u16x8 u; bfrag b; } c; c.u = u; return c.b;
}

// coherent (sc0 sc1, L3-direct) 16B fragment load as 2x 8B relaxed agent atomics
union frag_u { unsigned long long q[2]; bfrag b; u16x8 s; };
__device__ __forceinline__ frag_u ld_frag(const unsigned short* p) {
  frag_u u;
  u.q[0] = __hip_atomic_load((unsigned long long*)p,       __ATOMIC_RELAXED, __HIP_MEMORY_SCOPE_AGENT);
  u.q[1] = __hip_atomic_load((unsigned long long*)(p + 4), __ATOMIC_RELAXED, __HIP_MEMORY_SCOPE_AGENT);
  return u;
}
__device__ __forceinline__ void st4(unsigned short* p, unsigned v) {
  __hip_atomic_store((unsigned*)p, v, __ATOMIC_RELAXED, __HIP_MEMORY_SCOPE_AGENT);
}

// wait until all 32 group flags >= tgt; CALLED BY WAVE 0 ONLY (lanes 0..31 poll)
__device__ __forceinline__ void group_wait(unsigned* flags, int lane, unsigned tgt) {
  unsigned f = tgt;
  if (lane < 32) f = __hip_atomic_load(&flags[lane], __ATOMIC_RELAXED, __HIP_MEMORY_SCOPE_AGENT);
  while (__any((int)(f < tgt))) {
    __builtin_amdgcn_s_sleep(1);
    asm volatile("" ::: "memory");
    if (lane < 32) f = __hip_atomic_load(&flags[lane], __ATOMIC_RELAXED, __HIP_MEMORY_SCOPE_AGENT);
  }
}

// out(t)[r,c]: waves 0,1 of each WG; wave w computes col c=w for row r_g
__device__ __forceinline__ void out_row(const unsigned short* h2, int r_g, int w,
                                        int lane, const float* __restrict__ Wlin,
                                        const float* __restrict__ blin,
                                        float* __restrict__ out, int t) {
  const unsigned short* hp = h2 + r_g * NH + lane * 16;
  const float* wl = Wlin + w * NH + lane * 16;
  float s = 0.f;
#pragma unroll
  for (int j = 0; j < 2; ++j) {
    frag_u hv = ld_frag(hp + j * 8);
#pragma unroll
    for (int e = 0; e < 8; ++e) s = fmaf(bf2f(hv.s[e]), wl[j * 8 + e], s);
  }
#pragma unroll
  for (int m = 1; m < 64; m <<= 1) s += __shfl_xor(s, m);
  if (lane == 0) out[r_g * (2 * NT) + w * NT + t] = s + blin[w];
}

__global__ void __launch_bounds__(BLOCK, 2) rnn_kernel(
    const float* __restrict__ x,     // [B][2][T]
    const float* __restrict__ Wi1,   // [H][2]
    const float* __restrict__ Whh1,  // [H][H]
    const float* __restrict__ Wih2,  // [H][H]
    const float* __restrict__ Whh2,  // [H][H]
    const float* __restrict__ bih1,
    const float* __restrict__ bhh1,
    const float* __restrict__ bih2,
    const float* __restrict__ bhh2,
    const float* __restrict__ Wlin,  // [2][H]
    const float* __restrict__ blin,  // [2]
    float* __restrict__ out)         // [B][2][T]
{
  const int bid = blockIdx.x, tid = threadIdx.x;
  const int w = tid >> 6, lane = tid & 63;
  const int mb = bid >> 5, nb = bid & 31;   // group mb: rows [mb*32,+32); WG cols [nb*32,+32)
  unsigned* flags = g_flag + mb * 32;

  // my own flag only advances when I store it -> stable base sample
  const unsigned base = __hip_atomic_load(&flags[nb], __ATOMIC_RELAXED, __HIP_MEMORY_SCOPE_AGENT);

  // zero my group's rows of the parity-1 buffers (the t = -1 state), coherent stores
  {
    unsigned* z1 = (unsigned*)(g_h1 + BH + mb * 32 * NH);
    unsigned* z2 = (unsigned*)(g_h2 + BH + mb * 32 * NH);
    for (int i = tid; i < 16 * NH; i += BLOCK) {
      __hip_atomic_store(&z1[i], 0u, __ATOMIC_RELAXED, __HIP_MEMORY_SCOPE_AGENT);
      __hip_atomic_store(&z2[i], 0u, __ATOMIC_RELAXED, __HIP_MEMORY_SCOPE_AGENT);
    }
  }

  // ---- persistent weight fragments: wave w owns K-slice [w*128, +128), all 32 cols
  const int fr = lane & 15;
  const int ko = (lane >> 4) << 3;        // 0,8,16,24
  const int kbase = w * 128;
  bfrag w1[2][4], w2i[2][4], w2h[2][4];   // [col-half cf][k-step st]
#pragma unroll
  for (int cf = 0; cf < 2; ++cf)
#pragma unroll
    for (int st = 0; st < 4; ++st) {
      const int off = (nb * 32 + cf * 16 + fr) * NH + kbase + st * 32 + ko;
      w1[cf][st]  = cvt8(Whh1 + off);
      w2i[cf][st] = cvt8(Wih2 + off);
      w2h[cf][st] = cvt8(Whh2 + off);
    }

  // ---- per-thread epilogue constants (2 adjacent cols of one row)
  const int rl = tid >> 4, cl = (tid & 15) * 2;    // row 0..31, col even
  const int grow = mb * 32 + rl, gcol = nb * 32 + cl;
  const float b1s0 = bih1[gcol] + bhh1[gcol];
  const float b1s1 = bih1[gcol + 1] + bhh1[gcol + 1];
  const float b2s0 = bih2[gcol] + bhh2[gcol];
  const float b2s1 = bih2[gcol + 1] + bhh2[gcol + 1];
  const float wi00 = Wi1[gcol * 2],       wi01 = Wi1[gcol * 2 + 1];
  const float wi10 = Wi1[(gcol + 1) * 2], wi11 = Wi1[(gcol + 1) * 2 + 1];
  const float* xrow = x + grow * (2 * NT);

  __shared__ float redA[8][32][36];
  __shared__ float redB[8][32][36];

  const int arow0 = mb * 32 + fr;     // A-frag row base (+ mf*16)
  const int prow = (lane >> 4) << 2;  // C/D row base within 16x16 frag
  const int r_g = mb * 32 + nb;       // this WG's out row

  // preamble complete -> flag = base+1
  asm volatile("s_waitcnt vmcnt(0)" ::: "memory");
  __syncthreads();
  if (tid == 0)
    __hip_atomic_store(&flags[nb], base + 1u, __ATOMIC_RELAXED, __HIP_MEMORY_SCOPE_AGENT);

  // phase p: A(p)=h1(p) [p<NT] || B(p-1)=h2(p-1) [p>=1] || out(p-2) [p>=2]
  for (int p = 0; p <= NT; ++p) {
    const unsigned short* h1_prev = g_h1 + ((p + 1) & 1) * BH; // h1(p-1)
    const unsigned short* h2_pp   = g_h2 + (p & 1) * BH;       // h2(p-2)
    unsigned short* h1_cur = g_h1 + (p & 1) * BH;              // h1(p)
    unsigned short* h2_cur = g_h2 + ((p + 1) & 1) * BH;        // h2(p-1)

    // only wave 0 polls; everyone else parks at the barrier
    if (w == 0) group_wait(flags, lane, base + 1u + (unsigned)p);
    __syncthreads();
    __builtin_amdgcn_sched_barrier(0);   // keep loads below the wait

    f32x4 accA[2][2] = {}; f32x4 accB[2][2] = {};
#pragma unroll
    for (int mf = 0; mf < 2; ++mf) {
      const unsigned short* pa1 = h1_prev + (arow0 + mf * 16) * NH + kbase + ko;
      const unsigned short* pa2 = h2_pp   + (arow0 + mf * 16) * NH + kbase + ko;
#pragma unroll
      for (int st = 0; st < 4; ++st) {
        frag_u a1 = ld_frag(pa1 + st * 32);
        if (p < NT) {
          accA[mf][0] = __builtin_amdgcn_mfma_f32_16x16x32_bf16(a1.b, w1[0][st], accA[mf][0], 0, 0, 0);
          accA[mf][1] = __builtin_amdgcn_mfma_f32_16x16x32_bf16(a1.b, w1[1][st], accA[mf][1], 0, 0, 0);
        }
        if (p >= 1) {
          frag_u a2 = ld_frag(pa2 + st * 32);
          accB[mf][0] = __builtin_amdgcn_mfma_f32_16x16x32_bf16(a1.b, w2i[0][st], accB[mf][0], 0, 0, 0);
          accB[mf][1] = __builtin_amdgcn_mfma_f32_16x16x32_bf16(a1.b, w2i[1][st], accB[mf][1], 0, 0, 0);
          accB[mf][0] = __builtin_amdgcn_mfma_f32_16x16x32_bf16(a2.b, w2h[0][st], accB[mf][0], 0, 0, 0);
          accB[mf][1] = __builtin_amdgcn_mfma_f32_16x16x32_bf16(a2.b, w2h[1][st], accB[mf][1], 0, 0, 0);
        }
      }
    }

    // out projection for t=p-2 (h2(p-2) stable all phase), waves 0,1
    if (p >= 2 && w < 2)
      out_row(h2_pp, r_g, w, lane, Wlin, blin, out, p - 2);

    // k-partials to LDS  (C/D: col = lane&15, row = (lane>>4)*4 + r)
#pragma unroll
    for (int mf = 0; mf < 2; ++mf)
#pragma unroll
      for (int cf = 0; cf < 2; ++cf)
#pragma unroll
        for (int r = 0; r < 4; ++r) {
          redA[w][mf * 16 + prow + r][cf * 16 + fr] = accA[mf][cf][r];
          redB[w][mf * 16 + prow + r][cf * 16 + fr] = accB[mf][cf][r];
        }
    __syncthreads();

    // 8-way k-reduction + fused epilogue (2 adjacent cols per thread)
    float sA0 = 0.f, sA1 = 0.f, sB0 = 0.f, sB1 = 0.f;
#pragma unroll
    for (int u = 0; u < 8; ++u) {
      const float2 a = *reinterpret_cast<const float2*>(&redA[u][rl][cl]);
      const float2 b = *reinterpret_cast<const float2*>(&redB[u][rl][cl]);
      sA0 += a.x; sA1 += a.y; sB0 += b.x; sB1 += b.y;
    }
    if (p < NT) {
      const float x0 = xrow[p], x1 = xrow[NT + p];
      const float v0 = sA0 + b1s0 + x0 * wi00 + x1 * wi01;
      const float v1 = sA1 + b1s1 + x0 * wi10 + x1 * wi11;
      st4(h1_cur + grow * NH + gcol,
          (unsigned)f2bf(tanhf(v0)) | ((unsigned)f2bf(tanhf(v1)) << 16));
    }
    if (p >= 1) {
      const float v0 = sB0 + b2s0;
      const float v1 = sB1 + b2s1;
      st4(h2_cur + grow * NH + gcol,
          (unsigned)f2bf(tanhf(v0)) | ((unsigned)f2bf(tanhf(v1)) << 16));
    }

    // release: all my coherent writes acked, then publish phase completion
    asm volatile("s_waitcnt vmcnt(0)" ::: "memory");
    __syncthreads();
    if (tid == 0)
      __hip_atomic_store(&flags[nb], base + 2u + (unsigned)p, __ATOMIC_RELAXED, __HIP_MEMORY_SCOPE_AGENT);
  }

  // final output t = NT-1: needs h2(NT-1) (written at phase NT by my group)
  if (w == 0) group_wait(flags, lane, base + 2u + (unsigned)NT);
  __syncthreads();
  if (w < 2)
    out_row(g_h2 + BH, r_g, w, lane, Wlin, blin, out, NT - 1);
}

extern "C" void kernel_launch(void* const* d_in, const int* in_sizes, int n_in,
                              void* d_out, int out_size, void* d_ws, size_t ws_size,
                              hipStream_t stream) {
  (void)in_sizes; (void)n_in; (void)d_ws; (void)ws_size; (void)out_size;
  const float* x    = (const float*)d_in[0];
  const float* Wi1  = (const float*)d_in[1];
  const float* Whh1 = (const float*)d_in[2];
  const float* bih1 = (const float*)d_in[3];
  const float* bhh1 = (const float*)d_in[4];
  const float* Wih2 = (const float*)d_in[5];
  const float* Whh2 = (const float*)d_in[6];
  const float* bih2 = (const float*)d_in[7];
  const float* bhh2 = (const float*)d_in[8];
  const float* Wlin = (const float*)d_in[9];
  const float* blin = (const float*)d_in[10];
  float* out = (float*)d_out;

  void* args[] = { (void*)&x, (void*)&Wi1, (void*)&Whh1, (void*)&Wih2, (void*)&Whh2,
                   (void*)&bih1, (void*)&bhh1, (void*)&bih2, (void*)&bhh2,
                   (void*)&Wlin, (void*)&blin, (void*)&out };
  hipLaunchCooperativeKernel((void*)rnn_kernel, dim3(GRID_WGS), dim3(BLOCK),
                             args, 0, stream);
}

// Round 7
// 3437.074 us; speedup vs baseline: 13.4424x; 1.5215x over previous
//
#include <hip/hip_runtime.h>

#define NB 256      // batch
#define NT 512      // time steps
#define NH 1024     // hidden
#define BH (NB * NH)
#define GRID_WGS 256
#define BLOCK 512

typedef __attribute__((ext_vector_type(8))) __bf16 bfrag;
typedef __attribute__((ext_vector_type(4))) float f32x4;
typedef __attribute__((ext_vector_type(4))) unsigned u32x4;
typedef __attribute__((ext_vector_type(8))) unsigned short u16x8;
typedef unsigned short us;

// h1 double buffer (h1(t) in buf[t&1]); h2 TRIPLE buffer (h2(t) in buf[t%3])
__device__ __attribute__((aligned(16))) us g_h1[2 * BH];
__device__ __attribute__((aligned(16))) us g_h2[3 * BH];
// per-(group,slot) monotonic flags (never reset -> graph-replay safe)
__device__ __attribute__((aligned(128))) unsigned g_flag[GRID_WGS];

__device__ __forceinline__ us f2bf(float f) {
  union { float f; unsigned u; } v; v.f = f;
  unsigned r = v.u + 0x7FFFu + ((v.u >> 16) & 1u);  // RTE
  return (us)(r >> 16);
}
__device__ __forceinline__ float bf2f(us u) {
  union { unsigned u; float f; } v; v.u = ((unsigned)u) << 16;
  return v.f;
}

__device__ __forceinline__ bfrag cvt8(const float* __restrict__ p) {
  f32x4 a = *reinterpret_cast<const f32x4*>(p);
  f32x4 b = *reinterpret_cast<const f32x4*>(p + 4);
  u16x8 u;
#pragma unroll
  for (int i = 0; i < 4; ++i) { u[i] = f2bf(a[i]); u[i + 4] = f2bf(b[i]); }
  union { u16x8 u; bfrag b; } c; c.u = u; return c.b;
}

// ---- device-coherent (sc0 sc1: bypass L1 + L2, L3 coherence point) ops
union f16u { u32x4 v; bfrag b; u16x8 s; };
__device__ __forceinline__ u32x4 ld16_dev(const void* p) {
  u32x4 r;
  asm volatile("global_load_dwordx4 %0, %1, off sc0 sc1" : "=v"(r) : "v"(p));
  return r;   // caller must s_waitcnt before use
}
__device__ __forceinline__ unsigned ld4_dev(const void* p) {
  unsigned r;
  asm volatile("global_load_dword %0, %1, off sc0 sc1\n\ts_waitcnt vmcnt(0)"
               : "=v"(r) : "v"(p) : "memory");
  return r;
}
__device__ __forceinline__ void st4_dev(void* p, unsigned v) {
  asm volatile("global_store_dword %0, %1, off sc0 sc1" :: "v"(p), "v"(v) : "memory");
}

// all 64 lanes poll flags[lane & mask] until every polled flag >= tgt
__device__ __forceinline__ void wait_flags(const unsigned* f, int lane, int mask,
                                           unsigned tgt) {
  const unsigned* fp = f + (lane & mask);
  for (;;) {
    unsigned v = ld4_dev(fp);
    if (!__any((int)(v < tgt))) break;
    __builtin_amdgcn_s_sleep(1);
  }
}

// out(t)[r_g, c=w] = dot(h2(t)[r_g,:], Wlin[w,:]) + blin[w]; called by waves 0,1
__device__ __forceinline__ void out_row(const us* h2, int r_g, int w, int lane,
                                        const float* __restrict__ Wlin,
                                        const float* __restrict__ blin,
                                        float* __restrict__ out, int t) {
  const us* hp = h2 + r_g * NH + lane * 16;
  const float* wl = Wlin + w * NH + lane * 16;
  f16u h0, h1v;
  h0.v  = ld16_dev(hp);
  h1v.v = ld16_dev(hp + 8);
  asm volatile("s_waitcnt vmcnt(0)" ::: "memory");
  __builtin_amdgcn_sched_barrier(0);
  float s = 0.f;
#pragma unroll
  for (int e = 0; e < 8; ++e) {
    s = fmaf(bf2f(h0.s[e]),  wl[e],     s);
    s = fmaf(bf2f(h1v.s[e]), wl[8 + e], s);
  }
#pragma unroll
  for (int m = 1; m < 64; m <<= 1) s += __shfl_xor(s, m);
  if (lane == 0) out[r_g * (2 * NT) + w * NT + t] = s + blin[w];
}

__global__ void __launch_bounds__(BLOCK, 2) rnn_kernel(
    const float* __restrict__ x,     // [B][2][T]
    const float* __restrict__ Wi1,   // [H][2]
    const float* __restrict__ Whh1,  // [H][H]
    const float* __restrict__ Wih2,  // [H][H]
    const float* __restrict__ Whh2,  // [H][H]
    const float* __restrict__ bih1,
    const float* __restrict__ bhh1,
    const float* __restrict__ bih2,
    const float* __restrict__ bhh2,
    const float* __restrict__ Wlin,  // [2][H]
    const float* __restrict__ blin,  // [2]
    float* __restrict__ out)         // [B][2][T]
{
  const int bid = blockIdx.x, tid = threadIdx.x;
  const int w = tid >> 6, lane = tid & 63;
  const int mb = bid >> 5, nb = bid & 31;   // group mb: rows [mb*32,+32); WG cols [nb*32,+32)
  unsigned* gf = g_flag + mb * 32;

  // my own flag only advances when I store it -> stable base sample
  const unsigned fb = ld4_dev(&gf[nb]);

  // zero my tile of the t=-1 buffers: h1 buf[1], h2 buf[2]
  {
    const int zrow = tid >> 4, zc = tid & 15;           // 32 rows x 16 dwords
    const int off_d = ((mb * 32 + zrow) * NH + nb * 32) / 2;
    st4_dev((unsigned*)(g_h1 + BH)     + off_d + zc, 0u);
    st4_dev((unsigned*)(g_h2 + 2 * BH) + off_d + zc, 0u);
  }

  // ---- persistent weight fragments: wave w owns K-slice [w*128,+128), 32 cols
  const int fr = lane & 15;
  const int ko = (lane >> 4) << 3;        // 0,8,16,24
  const int kbase = w * 128;
  bfrag w1[2][4], w2i[2][4], w2h[2][4];   // [col-half cf][k-step st]
#pragma unroll
  for (int cf = 0; cf < 2; ++cf)
#pragma unroll
    for (int st = 0; st < 4; ++st) {
      const int off = (nb * 32 + cf * 16 + fr) * NH + kbase + st * 32 + ko;
      w1[cf][st]  = cvt8(Whh1 + off);
      w2i[cf][st] = cvt8(Wih2 + off);
      w2h[cf][st] = cvt8(Whh2 + off);
    }

  // ---- per-thread epilogue constants (2 adjacent cols of one row)
  const int rl = tid >> 4, cl = (tid & 15) * 2;    // row 0..31, col even
  const int grow = mb * 32 + rl, gcol = nb * 32 + cl;
  const float b1s0 = bih1[gcol] + bhh1[gcol];
  const float b1s1 = bih1[gcol + 1] + bhh1[gcol + 1];
  const float b2s0 = bih2[gcol] + bhh2[gcol];
  const float b2s1 = bih2[gcol + 1] + bhh2[gcol + 1];
  const float wi00 = Wi1[gcol * 2],       wi01 = Wi1[gcol * 2 + 1];
  const float wi10 = Wi1[(gcol + 1) * 2], wi11 = Wi1[(gcol + 1) * 2 + 1];
  const float* xrow = x + grow * (2 * NT);

  __shared__ float redA[8][32][36];
  __shared__ float redB[8][32][36];

  const int arow0 = mb * 32 + fr;     // A-frag row base (+ mf*16)
  const int prow = (lane >> 4) << 2;  // C/D row base within 16x16 frag
  const int r_g = bid;                // this WG's out row (mb*32 + nb)

  // preamble complete -> my flag = fb+1
  asm volatile("s_waitcnt vmcnt(0)" ::: "memory");
  __syncthreads();
  if (tid == 0) st4_dev(&gf[nb], fb + 1u);

  // h2 buf indices at phase p: out reads c0=p%3 (=h2(p-3)), pp reads c1=(p+1)%3
  // (=h2(p-2)), cur writes c2=(p+2)%3 (=h2(p-1))
  int c0 = 0, c1 = 1, c2 = 2;

  for (int p = 0; p <= NT; ++p) {
    const us* h1_prev = g_h1 + ((p + 1) & 1) * BH;
    us* h1_cur        = g_h1 + (p & 1) * BH;
    const us* h2_pp   = g_h2 + c1 * BH;
    us* h2_cur        = g_h2 + c2 * BH;
    const us* h2_out  = g_h2 + c0 * BH;

    const float x0 = xrow[p < NT ? p : 0], x1 = xrow[NT + (p < NT ? p : 0)];

    // wave w waits only on its 4 K-producer slots
    wait_flags(gf + w * 4, lane, 3, fb + 1u + (unsigned)p);
    __builtin_amdgcn_sched_barrier(0);

    // issue all 16 fragment loads (mf0: 8, mf1: 8), counted-wait overlap
    f16u a1[2][4], a2[2][4];
#pragma unroll
    for (int mf = 0; mf < 2; ++mf) {
      const us* pa1 = h1_prev + (arow0 + mf * 16) * NH + kbase + ko;
      const us* pa2 = h2_pp   + (arow0 + mf * 16) * NH + kbase + ko;
#pragma unroll
      for (int st = 0; st < 4; ++st) {
        a1[mf][st].v = ld16_dev(pa1 + st * 32);
        a2[mf][st].v = ld16_dev(pa2 + st * 32);
      }
    }

    f32x4 accA[2][2] = {}; f32x4 accB[2][2] = {};
    asm volatile("s_waitcnt vmcnt(8)" ::: "memory");   // mf0's 8 loads done
    __builtin_amdgcn_sched_barrier(0);
#pragma unroll
    for (int st = 0; st < 4; ++st) {
      accA[0][0] = __builtin_amdgcn_mfma_f32_16x16x32_bf16(a1[0][st].b, w1[0][st],  accA[0][0], 0, 0, 0);
      accA[0][1] = __builtin_amdgcn_mfma_f32_16x16x32_bf16(a1[0][st].b, w1[1][st],  accA[0][1], 0, 0, 0);
      accB[0][0] = __builtin_amdgcn_mfma_f32_16x16x32_bf16(a1[0][st].b, w2i[0][st], accB[0][0], 0, 0, 0);
      accB[0][1] = __builtin_amdgcn_mfma_f32_16x16x32_bf16(a1[0][st].b, w2i[1][st], accB[0][1], 0, 0, 0);
      accB[0][0] = __builtin_amdgcn_mfma_f32_16x16x32_bf16(a2[0][st].b, w2h[0][st], accB[0][0], 0, 0, 0);
      accB[0][1] = __builtin_amdgcn_mfma_f32_16x16x32_bf16(a2[0][st].b, w2h[1][st], accB[0][1], 0, 0, 0);
    }
    asm volatile("s_waitcnt vmcnt(0)" ::: "memory");   // mf1's loads done
    __builtin_amdgcn_sched_barrier(0);
#pragma unroll
    for (int st = 0; st < 4; ++st) {
      accA[1][0] = __builtin_amdgcn_mfma_f32_16x16x32_bf16(a1[1][st].b, w1[0][st],  accA[1][0], 0, 0, 0);
      accA[1][1] = __builtin_amdgcn_mfma_f32_16x16x32_bf16(a1[1][st].b, w1[1][st],  accA[1][1], 0, 0, 0);
      accB[1][0] = __builtin_amdgcn_mfma_f32_16x16x32_bf16(a1[1][st].b, w2i[0][st], accB[1][0], 0, 0, 0);
      accB[1][1] = __builtin_amdgcn_mfma_f32_16x16x32_bf16(a1[1][st].b, w2i[1][st], accB[1][1], 0, 0, 0);
      accB[1][0] = __builtin_amdgcn_mfma_f32_16x16x32_bf16(a2[1][st].b, w2h[0][st], accB[1][0], 0, 0, 0);
      accB[1][1] = __builtin_amdgcn_mfma_f32_16x16x32_bf16(a2[1][st].b, w2h[1][st], accB[1][1], 0, 0, 0);
    }

    // k-partials to LDS  (C/D: col = lane&15, row = (lane>>4)*4 + r)
#pragma unroll
    for (int mf = 0; mf < 2; ++mf)
#pragma unroll
      for (int cf = 0; cf < 2; ++cf)
#pragma unroll
        for (int r = 0; r < 4; ++r) {
          redA[w][mf * 16 + prow + r][cf * 16 + fr] = accA[mf][cf][r];
          redB[w][mf * 16 + prow + r][cf * 16 + fr] = accB[mf][cf][r];
        }

    // out(p-3): h2(p-3) complete (all slots passed phase p-1 waits) & triple-buffered
    if (p >= 3 && w < 2)
      out_row(h2_out, r_g, w, lane, Wlin, blin, out, p - 3);
    __syncthreads();

    // 8-way k-reduction + fused epilogue (2 adjacent cols per thread)
    float sA0 = 0.f, sA1 = 0.f, sB0 = 0.f, sB1 = 0.f;
#pragma unroll
    for (int u = 0; u < 8; ++u) {
      const float2 a = *reinterpret_cast<const float2*>(&redA[u][rl][cl]);
      const float2 b = *reinterpret_cast<const float2*>(&redB[u][rl][cl]);
      sA0 += a.x; sA1 += a.y; sB0 += b.x; sB1 += b.y;
    }
    if (p < NT) {
      const float v0 = sA0 + b1s0 + x0 * wi00 + x1 * wi01;
      const float v1 = sA1 + b1s1 + x0 * wi10 + x1 * wi11;
      st4_dev(h1_cur + grow * NH + gcol,
              (unsigned)f2bf(tanhf(v0)) | ((unsigned)f2bf(tanhf(v1)) << 16));
    }
    if (p >= 1) {
      const float v0 = sB0 + b2s0;
      const float v1 = sB1 + b2s1;
      st4_dev(h2_cur + grow * NH + gcol,
              (unsigned)f2bf(tanhf(v0)) | ((unsigned)f2bf(tanhf(v1)) << 16));
    }

    // release: coherent writes acked at L3, all waves done, then publish
    asm volatile("s_waitcnt vmcnt(0)" ::: "memory");
    __syncthreads();
    if (tid == 0) st4_dev(&gf[nb], fb + 2u + (unsigned)p);

    const int t = c0; c0 = c1; c1 = c2; c2 = t;   // rotate h2 buffers
  }

  // tail: out(NT-2), out(NT-1) need all producers finished phase NT
  wait_flags(gf, lane, 31, fb + 2u + (unsigned)NT);
  if (w < 2) {
    out_row(g_h2 + ((NT - 2) % 3) * BH, r_g, w, lane, Wlin, blin, out, NT - 2);
    out_row(g_h2 + ((NT - 1) % 3) * BH, r_g, w, lane, Wlin, blin, out, NT - 1);
  }
}

extern "C" void kernel_launch(void* const* d_in, const int* in_sizes, int n_in,
                              void* d_out, int out_size, void* d_ws, size_t ws_size,
                              hipStream_t stream) {
  (void)in_sizes; (void)n_in; (void)d_ws; (void)ws_size; (void)out_size;
  const float* x    = (const float*)d_in[0];
  const float* Wi1  = (const float*)d_in[1];
  const float* Whh1 = (const float*)d_in[2];
  const float* bih1 = (const float*)d_in[3];
  const float* bhh1 = (const float*)d_in[4];
  const float* Wih2 = (const float*)d_in[5];
  const float* Whh2 = (const float*)d_in[6];
  const float* bih2 = (const float*)d_in[7];
  const float* bhh2 = (const float*)d_in[8];
  const float* Wlin = (const float*)d_in[9];
  const float* blin = (const float*)d_in[10];
  float* out = (float*)d_out;

  void* args[] = { (void*)&x, (void*)&Wi1, (void*)&Whh1, (void*)&Wih2, (void*)&Whh2,
                   (void*)&bih1, (void*)&bhh1, (void*)&bih2, (void*)&bhh2,
                   (void*)&Wlin, (void*)&blin, (void*)&out };
  hipLaunchCooperativeKernel((void*)rnn_kernel, dim3(GRID_WGS), dim3(BLOCK),
                             args, 0, stream);
}